// Round 9
// baseline (113.368 us; speedup 1.0000x reference)
//
#include <hip/hip_runtime.h>
#include <cstddef>

typedef unsigned long long ull;

#define NPIX (1024 * 2048)
#define WW 2048
#define MAXC 200
#define GRIDB 256
#define BLKT 1024
#define PXT 8
#define NW 16
#define TAGSH 56
#define KMASK ((1ull << 52) - 1)
#define ZMASK ((1ull << 48) - 1)

union F8 { float4 v[2]; float f[8]; };
union I8 { int4 v[2]; int f[8]; };

__device__ inline ull AL(ull* p) { return __hip_atomic_load(p, __ATOMIC_RELAXED, __HIP_MEMORY_SCOPE_AGENT); }
__device__ inline void ASu(ull* p, ull v) { __hip_atomic_store(p, v, __ATOMIC_RELAXED, __HIP_MEMORY_SCOPE_AGENT); }
__device__ inline void ASI(int* p, int v) { __hip_atomic_store(p, v, __ATOMIC_RELAXED, __HIP_MEMORY_SCOPE_AGENT); }
__device__ inline int ALI(int* p) { return __hip_atomic_load(p, __ATOMIC_RELAXED, __HIP_MEMORY_SCOPE_AGENT); }

__device__ inline ull shfl_down_u64(ull v, int o) {
  unsigned lo = (unsigned)v, hi = (unsigned)(v >> 32);
  lo = __shfl_down(lo, o, 64);
  hi = __shfl_down(hi, o, 64);
  return ((ull)hi << 32) | lo;
}
// wave tuple reduce: argmax by k carrying (a,c); field-wise sum of z.
__device__ inline void tred4(ull& k, ull& z, ull& a, ull& c) {
  #pragma unroll
  for (int o = 32; o > 0; o >>= 1) {
    ull k2 = shfl_down_u64(k, o), z2 = shfl_down_u64(z, o),
        a2 = shfl_down_u64(a, o), c2 = shfl_down_u64(c, o);
    if (k2 > k) { k = k2; a = a2; c = c2; }
    z += z2;
  }
}
// compile-time-safe 8-way register select (no scratch)
__device__ inline float sel8(const F8& x, int j) {
  const float4 lo = x.v[0], hi = x.v[1];
  float hx = (j & 4) ? hi.x : lo.x, hy = (j & 4) ? hi.y : lo.y;
  float hz = (j & 4) ? hi.z : lo.z, hw = (j & 4) ? hi.w : lo.w;
  float a = (j & 2) ? hz : hx;
  float c = (j & 2) ? hw : hy;
  return (j & 1) ? c : a;
}

// CAP < MAXC  -> diagnostic: run CAP sweep iterations, write sink, exit.
// CAP >= MAXC -> real kernel: full loop + epilogue + output.
template<int CAP>
__global__ __launch_bounds__(BLKT) void k_all(
    const float* __restrict__ pred,
    ull* __restrict__ slots,        // [GRIDB][8]: 6 tagged words per block line
    ull* __restrict__ root,         // [8]: one tagged root line
    ull* __restrict__ sink,         // [GRIDB] diag sink
    int* __restrict__ prevp, int* __restrict__ nowp,
    int* __restrict__ out)
{
  __shared__ ull lsb[NW][4];        // sweep-phase wave partials {K,Z,A,C}
  __shared__ ull lsa[4][4];         // reducer poll-phase wave partials
  __shared__ ull lroot[6];          // broadcast root: K,Z,c0,c1,s0,s1 (raw)
  __shared__ int lbad[MAXC];

  const int b = blockIdx.x, tid = threadIdx.x;
  const int wid = tid >> 6, lane = tid & 63;
  const int base = (b * BLKT + tid) * PXT;
  const float dxs = 2.0f / 2047.0f;   // linspace(0,2,2048) step
  const float dys = 1.0f / 1023.0f;   // linspace(0,1,1024) step

  F8 Av, Bv, Sv, E0, E1;    // spatial_emb x/y, seed score (sign=clustered), exp(10*sigma)
  ull iv = 0;               // 8 inst labels (bytes)
  unsigned pp = 0;          // previous iteration's proposal bits

  // ---------------- pre-phase: everything -> registers --------------------
  {
    F8 P, Q;
    const int h = base >> 11, wb = base & (WW - 1);
    const float yv = __fmul_rn((float)h, dys);
    P.v[0] = *(const float4*)(pred + base);     P.v[1] = *(const float4*)(pred + base + 4);
    #pragma unroll
    for (int j = 0; j < PXT; j++)
      Av.f[j] = __fadd_rn(tanhf(P.f[j]), __fmul_rn((float)(wb + j), dxs));
    P.v[0] = *(const float4*)(pred + NPIX + base); P.v[1] = *(const float4*)(pred + NPIX + base + 4);
    #pragma unroll
    for (int j = 0; j < PXT; j++)
      Bv.f[j] = __fadd_rn(tanhf(P.f[j]), yv);
    P.v[0] = *(const float4*)(pred + 2 * NPIX + base); P.v[1] = *(const float4*)(pred + 2 * NPIX + base + 4);
    #pragma unroll
    for (int j = 0; j < PXT; j++)
      E0.f[j] = expf(__fmul_rn(P.f[j], 10.0f));
    P.v[0] = *(const float4*)(pred + 3 * NPIX + base); P.v[1] = *(const float4*)(pred + 3 * NPIX + base + 4);
    #pragma unroll
    for (int j = 0; j < PXT; j++)
      E1.f[j] = expf(__fmul_rn(P.f[j], 10.0f));
    P.v[0] = *(const float4*)(pred + 5 * NPIX + base); P.v[1] = *(const float4*)(pred + 5 * NPIX + base + 4);
    Q.v[0] = *(const float4*)(pred + 6 * NPIX + base); Q.v[1] = *(const float4*)(pred + 6 * NPIX + base + 4);
    #pragma unroll
    for (int j = 0; j < PXT; j++) {
      float a = P.f[j], bb = Q.f[j];
      float mx = fmaxf(a, bb);
      float ea = expf(__fsub_rn(a, mx));
      float eb = expf(__fsub_rn(bb, mx));
      Sv.f[j] = __fdiv_rn(eb, __fadd_rn(ea, eb));   // softmax(...)[1], bit-exact vs ref
    }
    float bsc = 0.0f; int bj = 0, cnt = 0;
    #pragma unroll
    for (int j = 0; j < PXT; j++) {
      float s = Sv.f[j];
      bool mm = s > 0.5f;
      cnt += mm ? 1 : 0;
      float sc = mm ? s : 0.0f;
      if (sc > bsc) { bsc = sc; bj = j; }
    }
    ull bk = ((ull)__float_as_uint(bsc) << 21) | (ull)(0x1FFFFFu - (unsigned)(base + bj));
    ull bz = ((ull)(unsigned)cnt) << 24;
    ull pa = ((ull)__float_as_uint(sel8(Av, bj)) << 32) | __float_as_uint(sel8(Bv, bj));
    ull pc = ((ull)__float_as_uint(sel8(E0, bj)) << 32) | __float_as_uint(sel8(E1, bj));
    tred4(bk, bz, pa, pc);
    if (lane == 0) { lsb[wid][0] = bk; lsb[wid][1] = bz; lsb[wid][2] = pa; lsb[wid][3] = pc; }
    if (b == 0)
      for (int c = tid; c < MAXC; c += BLKT) { ASI(&nowp[c], 0); ASI(&prevp[c], 0); }
    __syncthreads();
    if (wid == 0) {
      ull k = 0, z = 0, a = 0, c = 0;
      if (lane < NW) { k = lsb[lane][0]; z = lsb[lane][1]; a = lsb[lane][2]; c = lsb[lane][3]; }
      #pragma unroll
      for (int o = 8; o > 0; o >>= 1) {
        ull k2 = shfl_down_u64(k, o), z2 = shfl_down_u64(z, o),
            a2 = shfl_down_u64(a, o), c2 = shfl_down_u64(c, o);
        if (k2 > k) { k = k2; a = a2; c = c2; }
        z += z2;
      }
      if (lane == 0) {
        ull* sl = slots + (size_t)b * 8;
        const ull tw = 1ull << TAGSH;
        ASu(sl + 0, tw | k); ASu(sl + 1, tw | z);
        ASu(sl + 2, tw | (a >> 32)); ASu(sl + 3, tw | (a & 0xFFFFFFFFull));
        ASu(sl + 4, tw | (c >> 32)); ASu(sl + 5, tw | (c & 0xFFFFFFFFull));
      }
    }
  }

  // ---------------- main loop: winner-reducer + single root line ----------
  int count = 1, rem = 0, tstop = 0, rb = 0;
  ull K = 0, Z = 0;
  for (int t = 0; t < MAXC + 2; ++t) {
    const unsigned tg = (unsigned)(t + 1);
    if (b == rb) {                                   // ---- reducer path ----
      if (tid < GRIDB) {
        ull* sl = slots + (size_t)tid * 8;
        ull w0, w1, w2, w3, w4, w5;
        for (;;) {
          w0 = AL(sl + 0); w1 = AL(sl + 1); w2 = AL(sl + 2);
          w3 = AL(sl + 3); w4 = AL(sl + 4); w5 = AL(sl + 5);
          if (((unsigned)(w0 >> TAGSH) == tg) & ((unsigned)(w1 >> TAGSH) == tg) &
              ((unsigned)(w2 >> TAGSH) == tg) & ((unsigned)(w3 >> TAGSH) == tg) &
              ((unsigned)(w4 >> TAGSH) == tg) & ((unsigned)(w5 >> TAGSH) == tg)) break;
        }
        ull k = w0 & KMASK, z = w1 & ZMASK;
        ull a = ((w2 & 0xFFFFFFFFull) << 32) | (w3 & 0xFFFFFFFFull);
        ull c = ((w4 & 0xFFFFFFFFull) << 32) | (w5 & 0xFFFFFFFFull);
        tred4(k, z, a, c);
        if (lane == 0) { lsa[wid][0] = k; lsa[wid][1] = z; lsa[wid][2] = a; lsa[wid][3] = c; }
      }
      __syncthreads();
      if (tid == 0) {
        ull k = lsa[0][0], z = lsa[0][1], a = lsa[0][2], c = lsa[0][3];
        #pragma unroll
        for (int i = 1; i < 4; i++) {
          ull kk = lsa[i][0];
          if (kk > k) { k = kk; a = lsa[i][2]; c = lsa[i][3]; }
          z += lsa[i][1];
        }
        const ull tw = ((ull)tg) << TAGSH;
        ASu(root + 1, tw | z);
        ASu(root + 2, tw | (a >> 32)); ASu(root + 3, tw | (a & 0xFFFFFFFFull));
        ASu(root + 4, tw | (c >> 32)); ASu(root + 5, tw | (c & 0xFFFFFFFFull));
        ASu(root + 0, tw | k);
        lroot[0] = k; lroot[1] = z;
        lroot[2] = a >> 32; lroot[3] = a & 0xFFFFFFFFull;
        lroot[4] = c >> 32; lroot[5] = c & 0xFFFFFFFFull;
      }
      __syncthreads();
    } else {                                         // ---- consumer path ---
      if (wid == 0) {
        const int q = lane & 7;
        ull w;
        for (;;) {
          w = AL(root + q);
          int ok = (q >= 6) || ((unsigned)(w >> TAGSH) == tg);
          if (__all(ok)) break;
          __builtin_amdgcn_s_sleep(1);
        }
        if (lane < 6)
          lroot[lane] = (lane == 0) ? (w & KMASK) : (lane == 1) ? (w & ZMASK)
                                                                : (w & 0xFFFFFFFFull);
      }
      __syncthreads();
    }
    K = lroot[0]; Z = lroot[1];
    const float c0 = __uint_as_float((unsigned)lroot[2]);
    const float c1 = __uint_as_float((unsigned)lroot[3]);
    const float s0 = __uint_as_float((unsigned)lroot[4]);
    const float s1 = __uint_as_float((unsigned)lroot[5]);

    // bookkeeping for iteration t-1 (redundant per-thread, deterministic)
    bool accP = false; int labP = 0;
    if (t == 0) {
      rem = (int)((Z >> 24) & 0xFFFFFF);
    } else {
      int ps = (int)((Z >> 24) & 0xFFFFFF), ui = (int)(Z & 0xFFFFFF);
      accP = (ps > 160) &&
             (__fdiv_rn((float)(ui - 1), fmaxf((float)ps, 1.0f)) > 0.5f);
      if (accP) {
        labP = count;
        if (b == 0 && tid == 0) ASI(&prevp[count], ps);
        count++;
      }
      rem -= ui;
    }
    if (accP && pp) {
      #pragma unroll
      for (int j = 0; j < PXT; j++)
        if ((pp >> j) & 1) iv = (iv & ~(0xFFull << (8 * j))) | ((ull)(unsigned)labP << (8 * j));
    }
    if constexpr (CAP < MAXC) {
      if (t >= CAP) { tstop = t; break; }            // diagnostic cutoff
    }
    if (!((rem > 160) && (count < MAXC))) { tstop = t; break; }
    const float score = __uint_as_float((unsigned)((K >> 21) & 0x7FFFFFFF));
    if (score < 0.5f) { tstop = t; break; }
    const int sidx = 0x1FFFFF - (int)(K & 0x1FFFFF);
    rb = sidx >> 13;                                 // winner block = next reducer

    // register-only sweep (expf only within 5.5e-5 window of the threshold)
    float bsc = 0.0f; int bj = 0, psl = 0, uil = 0; unsigned ppn = 0;
    #pragma unroll
    for (int j = 0; j < PXT; j++) {
      float s = Sv.f[j];
      float d0 = __fsub_rn(Av.f[j], c0);
      float d1 = __fsub_rn(Bv.f[j], c1);
      float tt = __fadd_rn(__fmul_rn(__fmul_rn(d0, d0), s0),
                           __fmul_rn(__fmul_rn(d1, d1), s1));
      bool dok = (tt <= 0.693120f);
      if (__builtin_expect((!dok) && (tt < 0.693175f), 0))
        dok = (expf(-tt) > 0.5f);
      bool pr = dok && (fabsf(s) > 0.5f);
      if (pr) {
        ppn |= 1u << j;
        psl++;
        if (s > 0.5f) { uil++; s = -s; Sv.f[j] = s; }
      }
      float sc = (s > 0.5f) ? s : 0.0f;
      if (sc > bsc) { bsc = sc; bj = j; }
    }
    pp = ppn;
    ull bk = ((ull)__float_as_uint(bsc) << 21) | (ull)(0x1FFFFFu - (unsigned)(base + bj));
    ull bz = ((ull)(unsigned)psl << 24) | (unsigned)uil;
    ull pa = ((ull)__float_as_uint(sel8(Av, bj)) << 32) | __float_as_uint(sel8(Bv, bj));
    ull pc = ((ull)__float_as_uint(sel8(E0, bj)) << 32) | __float_as_uint(sel8(E1, bj));
    tred4(bk, bz, pa, pc);
    if (lane == 0) { lsb[wid][0] = bk; lsb[wid][1] = bz; lsb[wid][2] = pa; lsb[wid][3] = pc; }
    __syncthreads();                                 // S2
    if (wid == 0) {
      ull k = 0, z = 0, a = 0, c = 0;
      if (lane < NW) { k = lsb[lane][0]; z = lsb[lane][1]; a = lsb[lane][2]; c = lsb[lane][3]; }
      #pragma unroll
      for (int o = 8; o > 0; o >>= 1) {
        ull k2 = shfl_down_u64(k, o), z2 = shfl_down_u64(z, o),
            a2 = shfl_down_u64(a, o), c2 = shfl_down_u64(c, o);
        if (k2 > k) { k = k2; a = a2; c = c2; }
        z += z2;
      }
      if (lane == 0) {
        ull* sl = slots + (size_t)b * 8;
        const ull tw = ((ull)(unsigned)(t + 2)) << TAGSH;
        ASu(sl + 0, tw | k); ASu(sl + 1, tw | z);
        ASu(sl + 2, tw | (a >> 32)); ASu(sl + 3, tw | (a & 0xFFFFFFFFull));
        ASu(sl + 4, tw | (c >> 32)); ASu(sl + 5, tw | (c & 0xFFFFFFFFull));
      }
    }
  }

  if constexpr (CAP < MAXC) {                        // diagnostic: sink & exit
    if (tid == 0)
      ASu(&sink[b], K + Z + ((ull)(unsigned)count << 8) + ((ull)(unsigned)rem << 32));
    return;
  } else {
  // ---------------- epilogue: bincount(skip 0) -> barrier -> bad -> out ---
  for (int c = tid; c < MAXC; c += BLKT) lbad[c] = 0;
  __syncthreads();
  {
    int cur = -1, acc = 0;
    #pragma unroll
    for (int j = 0; j < PXT; j++) {
      int lb = (int)((iv >> (8 * j)) & 0xFF);
      if (lb == cur) acc++;
      else { if (cur > 0) atomicAdd(&lbad[cur], acc); cur = lb; acc = 1; }
    }
    if (cur > 0) atomicAdd(&lbad[cur], acc);
  }
  __syncthreads();
  for (int c = tid + 1; c < MAXC; c += BLKT)
    if (lbad[c]) atomicAdd(&nowp[c], lbad[c]);
  __syncthreads();                                   // drains this block's atomics
  {
    const unsigned etg = (unsigned)(tstop + 2);
    if (tid == 0) ASu(slots + (size_t)b * 8, ((ull)etg) << TAGSH);
    if (b == rb) {
      if (tid < GRIDB) {
        ull* sl = slots + (size_t)tid * 8;
        while ((unsigned)(AL(sl) >> TAGSH) != etg) {}
      }
      __syncthreads();
      if (tid == 0) ASu(root, ((ull)etg) << TAGSH);
    } else {
      if (wid == 0) {
        for (;;) {
          ull w = AL(root);
          if ((unsigned)(w >> TAGSH) == etg) break;
          __builtin_amdgcn_s_sleep(1);
        }
      }
    }
    __syncthreads();
  }
  if (tid < MAXC) {
    int c = tid;
    int nw = (c == 0) ? 0 : ALI(&nowp[c]);
    int pv = ALI(&prevp[c]);
    float ratio = __fdiv_rn((float)nw, (float)(pv > 1 ? pv : 1));
    int bd = (nw != pv) && (nw > 0) && ((nw < 3 * 160) || (ratio < 0.5f));
    if (c == 0) bd = 0;
    lbad[c] = bd;
  }
  __syncthreads();
  {
    I8 O;
    #pragma unroll
    for (int j = 0; j < PXT; j++) {
      int v = (int)((iv >> (8 * j)) & 0xFF);
      O.f[j] = lbad[v] ? 0 : v;
    }
    *(int4*)(out + base) = O.v[0];
    *(int4*)(out + base + 4) = O.v[1];
  }
  }
}

extern "C" void kernel_launch(void* const* d_in, const int* in_sizes, int n_in,
                              void* d_out, int out_size, void* d_ws, size_t ws_size,
                              hipStream_t stream) {
  const float* pred = (const float*)d_in[0];
  char* ws = (char*)d_ws;
  // 4 independent control regions (32 KB each): slots(16K) | root(64) | sink
  auto slotsOf = [&](int r) { return (ull*)(ws + (size_t)r * 32768); };
  auto rootOf  = [&](int r) { return (ull*)(ws + (size_t)r * 32768 + 16384); };
  auto sinkOf  = [&](int r) { return (ull*)(ws + (size_t)r * 32768 + 16448); };
  int* prevp = (int*)(ws + 4 * 32768);
  int* nowp  = (int*)(ws + 4 * 32768 + MAXC * 4);
  int* out = (int*)d_out;

  hipMemsetAsync(ws, 0, 4 * 32768, stream);          // clean tags every call

  // real kernel first (produces output)
  hipLaunchKernelGGL((k_all<MAXC>), dim3(GRIDB), dim3(BLKT), 0, stream,
                     pred, slotsOf(0), rootOf(0), sinkOf(0), prevp, nowp, out);
  // diagnostics: phase-cost probes (durations via rocprof; output untouched)
  hipLaunchKernelGGL((k_all<0>), dim3(GRIDB), dim3(BLKT), 0, stream,
                     pred, slotsOf(1), rootOf(1), sinkOf(1), prevp, nowp, out);
  hipLaunchKernelGGL((k_all<1>), dim3(GRIDB), dim3(BLKT), 0, stream,
                     pred, slotsOf(2), rootOf(2), sinkOf(2), prevp, nowp, out);
  hipLaunchKernelGGL((k_all<6>), dim3(GRIDB), dim3(BLKT), 0, stream,
                     pred, slotsOf(3), rootOf(3), sinkOf(3), prevp, nowp, out);
}

// Round 10
// 46.251 us; speedup vs baseline: 2.4512x; 2.4512x over previous
//
#include <hip/hip_runtime.h>
#include <cstddef>

typedef unsigned long long ull;

#define NPIX (1024 * 2048)
#define WW 2048
#define MAXC 200
#define GRIDB 256
#define BLKT 1024
#define PXT 8
#define NW 16
#define TAGSH 56
#define KMASK ((1ull << 52) - 1)
#define ZMASK ((1ull << 48) - 1)

union F8 { float4 v[2]; float f[8]; };
union I8 { int4 v[2]; int f[8]; };

__device__ inline ull AL(ull* p) { return __hip_atomic_load(p, __ATOMIC_RELAXED, __HIP_MEMORY_SCOPE_AGENT); }
__device__ inline void ASu(ull* p, ull v) { __hip_atomic_store(p, v, __ATOMIC_RELAXED, __HIP_MEMORY_SCOPE_AGENT); }
__device__ inline void ASI(int* p, int v) { __hip_atomic_store(p, v, __ATOMIC_RELAXED, __HIP_MEMORY_SCOPE_AGENT); }
__device__ inline int ALI(int* p) { return __hip_atomic_load(p, __ATOMIC_RELAXED, __HIP_MEMORY_SCOPE_AGENT); }

__device__ inline ull shfl_down_u64(ull v, int o) {
  unsigned lo = (unsigned)v, hi = (unsigned)(v >> 32);
  lo = __shfl_down(lo, o, 64);
  hi = __shfl_down(hi, o, 64);
  return ((ull)hi << 32) | lo;
}
// wave tuple reduce: argmax by k carrying (a,c); field-wise sum of z.
__device__ inline void tred4(ull& k, ull& z, ull& a, ull& c) {
  #pragma unroll
  for (int o = 32; o > 0; o >>= 1) {
    ull k2 = shfl_down_u64(k, o), z2 = shfl_down_u64(z, o),
        a2 = shfl_down_u64(a, o), c2 = shfl_down_u64(c, o);
    if (k2 > k) { k = k2; a = a2; c = c2; }
    z += z2;
  }
}
// compile-time-safe 8-way register select (no scratch)
__device__ inline float sel8(const F8& x, int j) {
  const float4 lo = x.v[0], hi = x.v[1];
  float hx = (j & 4) ? hi.x : lo.x, hy = (j & 4) ? hi.y : lo.y;
  float hz = (j & 4) ? hi.z : lo.z, hw = (j & 4) ? hi.w : lo.w;
  float a = (j & 2) ? hz : hx;
  float c = (j & 2) ? hw : hy;
  return (j & 1) ? c : a;
}
// block publish: cook raw (p2,p3) payload into (s0,s1) and store 6 tagged words
__device__ inline void publish(ull* sl, ull tw, ull k, ull z, ull a, ull c) {
  float p2w = __uint_as_float((unsigned)(c >> 32));
  float p3w = __uint_as_float((unsigned)(c & 0xFFFFFFFFull));
  ull s0b = __float_as_uint(expf(__fmul_rn(p2w, 10.0f)));
  ull s1b = __float_as_uint(expf(__fmul_rn(p3w, 10.0f)));
  ASu(sl + 0, tw | k); ASu(sl + 1, tw | z);
  ASu(sl + 2, tw | (a >> 32)); ASu(sl + 3, tw | (a & 0xFFFFFFFFull));
  ASu(sl + 4, tw | s0b); ASu(sl + 5, tw | s1b);
}

__global__ __launch_bounds__(BLKT) void k_all(
    const float* __restrict__ pred,
    ull* __restrict__ slots,        // [GRIDB][8]: 6 tagged words per block line
    ull* __restrict__ root,         // [8]: one tagged root line
    int* __restrict__ prevp, int* __restrict__ nowp,
    int* __restrict__ out)
{
  __shared__ ull lsb[NW][4];        // sweep-phase wave partials {K,Z,A,C}
  __shared__ ull lsa[4][4];         // reducer poll-phase wave partials
  __shared__ ull lroot[6];          // broadcast root: K,Z,c0,c1,s0,s1 (raw words)
  __shared__ int lbad[MAXC];

  const int b = blockIdx.x, tid = threadIdx.x;
  const int wid = tid >> 6, lane = tid & 63;
  const int base = (b * BLKT + tid) * PXT;
  const float dxs = 2.0f / 2047.0f;   // linspace(0,2,2048) step
  const float dys = 1.0f / 1023.0f;   // linspace(0,1,1024) step

  F8 Av, Bv, Sv, R2, R3;    // spatial_emb x/y, seed score (sign=clustered), raw sigma
  ull iv = 0;               // 8 inst labels (bytes)
  unsigned pp = 0;          // previous iteration's proposal bits

  // -------- pre-phase: ALL plane loads issued up front, then compute ------
  {
    F8 L0, L1, L5, L6;
    // 12 independent float4 loads — all in flight simultaneously
    L0.v[0] = *(const float4*)(pred + base);
    L0.v[1] = *(const float4*)(pred + base + 4);
    L1.v[0] = *(const float4*)(pred + NPIX + base);
    L1.v[1] = *(const float4*)(pred + NPIX + base + 4);
    R2.v[0] = *(const float4*)(pred + 2 * NPIX + base);
    R2.v[1] = *(const float4*)(pred + 2 * NPIX + base + 4);
    R3.v[0] = *(const float4*)(pred + 3 * NPIX + base);
    R3.v[1] = *(const float4*)(pred + 3 * NPIX + base + 4);
    L5.v[0] = *(const float4*)(pred + 5 * NPIX + base);
    L5.v[1] = *(const float4*)(pred + 5 * NPIX + base + 4);
    L6.v[0] = *(const float4*)(pred + 6 * NPIX + base);
    L6.v[1] = *(const float4*)(pred + 6 * NPIX + base + 4);

    const int h = base >> 11, wb = base & (WW - 1);
    const float yv = __fmul_rn((float)h, dys);
    #pragma unroll
    for (int j = 0; j < PXT; j++)
      Av.f[j] = __fadd_rn(tanhf(L0.f[j]), __fmul_rn((float)(wb + j), dxs));
    #pragma unroll
    for (int j = 0; j < PXT; j++)
      Bv.f[j] = __fadd_rn(tanhf(L1.f[j]), yv);
    #pragma unroll
    for (int j = 0; j < PXT; j++) {
      float a = L5.f[j], bb = L6.f[j];
      float mx = fmaxf(a, bb);
      float ea = expf(__fsub_rn(a, mx));
      float eb = expf(__fsub_rn(bb, mx));
      Sv.f[j] = __fdiv_rn(eb, __fadd_rn(ea, eb));   // softmax(...)[1], bit-exact vs ref
    }
    float bsc = 0.0f; int bj = 0, cnt = 0;
    #pragma unroll
    for (int j = 0; j < PXT; j++) {
      float s = Sv.f[j];
      bool mm = s > 0.5f;
      cnt += mm ? 1 : 0;
      float sc = mm ? s : 0.0f;
      if (sc > bsc) { bsc = sc; bj = j; }
    }
    ull bk = ((ull)__float_as_uint(bsc) << 21) | (ull)(0x1FFFFFu - (unsigned)(base + bj));
    ull bz = ((ull)(unsigned)cnt) << 24;
    ull pa = ((ull)__float_as_uint(sel8(Av, bj)) << 32) | __float_as_uint(sel8(Bv, bj));
    ull pc = ((ull)__float_as_uint(sel8(R2, bj)) << 32) | __float_as_uint(sel8(R3, bj));
    tred4(bk, bz, pa, pc);
    if (lane == 0) { lsb[wid][0] = bk; lsb[wid][1] = bz; lsb[wid][2] = pa; lsb[wid][3] = pc; }
    if (b == 0)
      for (int c = tid; c < MAXC; c += BLKT) { ASI(&nowp[c], 0); ASI(&prevp[c], 0); }
    __syncthreads();
    if (wid == 0) {
      ull k = 0, z = 0, a = 0, c = 0;
      if (lane < NW) { k = lsb[lane][0]; z = lsb[lane][1]; a = lsb[lane][2]; c = lsb[lane][3]; }
      #pragma unroll
      for (int o = 8; o > 0; o >>= 1) {
        ull k2 = shfl_down_u64(k, o), z2 = shfl_down_u64(z, o),
            a2 = shfl_down_u64(a, o), c2 = shfl_down_u64(c, o);
        if (k2 > k) { k = k2; a = a2; c = c2; }
        z += z2;
      }
      if (lane == 0) publish(slots + (size_t)b * 8, 1ull << TAGSH, k, z, a, c);
    }
  }

  // ---------------- main loop: winner-reducer + single root line ----------
  int count = 1, rem = 0, tstop = 0, rb = 0;
  for (int t = 0; t < MAXC + 2; ++t) {
    const unsigned tg = (unsigned)(t + 1);
    if (b == rb) {                                   // ---- reducer path ----
      if (tid < GRIDB) {
        ull* sl = slots + (size_t)tid * 8;
        ull w0, w1, w2, w3, w4, w5;
        for (;;) {
          w0 = AL(sl + 0); w1 = AL(sl + 1); w2 = AL(sl + 2);
          w3 = AL(sl + 3); w4 = AL(sl + 4); w5 = AL(sl + 5);
          if (((unsigned)(w0 >> TAGSH) == tg) & ((unsigned)(w1 >> TAGSH) == tg) &
              ((unsigned)(w2 >> TAGSH) == tg) & ((unsigned)(w3 >> TAGSH) == tg) &
              ((unsigned)(w4 >> TAGSH) == tg) & ((unsigned)(w5 >> TAGSH) == tg)) break;
        }
        ull k = w0 & KMASK, z = w1 & ZMASK;
        ull a = ((w2 & 0xFFFFFFFFull) << 32) | (w3 & 0xFFFFFFFFull);
        ull c = ((w4 & 0xFFFFFFFFull) << 32) | (w5 & 0xFFFFFFFFull);
        tred4(k, z, a, c);
        if (lane == 0) { lsa[wid][0] = k; lsa[wid][1] = z; lsa[wid][2] = a; lsa[wid][3] = c; }
      }
      __syncthreads();
      if (tid == 0) {
        ull k = lsa[0][0], z = lsa[0][1], a = lsa[0][2], c = lsa[0][3];
        #pragma unroll
        for (int i = 1; i < 4; i++) {
          ull kk = lsa[i][0];
          if (kk > k) { k = kk; a = lsa[i][2]; c = lsa[i][3]; }
          z += lsa[i][1];
        }
        const ull tw = ((ull)tg) << TAGSH;
        ASu(root + 1, tw | z);
        ASu(root + 2, tw | (a >> 32)); ASu(root + 3, tw | (a & 0xFFFFFFFFull));
        ASu(root + 4, tw | (c >> 32)); ASu(root + 5, tw | (c & 0xFFFFFFFFull));
        ASu(root + 0, tw | k);
        lroot[0] = k; lroot[1] = z;
        lroot[2] = a >> 32; lroot[3] = a & 0xFFFFFFFFull;
        lroot[4] = c >> 32; lroot[5] = c & 0xFFFFFFFFull;
      }
      __syncthreads();
    } else {                                         // ---- consumer path ---
      if (wid == 0) {
        const int q = lane & 7;
        ull w;
        for (;;) {
          w = AL(root + q);
          int ok = (q >= 6) || ((unsigned)(w >> TAGSH) == tg);
          if (__all(ok)) break;
          __builtin_amdgcn_s_sleep(1);
        }
        if (lane < 6)
          lroot[lane] = (lane == 0) ? (w & KMASK) : (lane == 1) ? (w & ZMASK)
                                                                : (w & 0xFFFFFFFFull);
      }
      __syncthreads();
    }
    const ull K = lroot[0], Z = lroot[1];
    const float c0 = __uint_as_float((unsigned)lroot[2]);
    const float c1 = __uint_as_float((unsigned)lroot[3]);
    const float s0 = __uint_as_float((unsigned)lroot[4]);
    const float s1 = __uint_as_float((unsigned)lroot[5]);

    // bookkeeping for iteration t-1 (redundant per-thread, deterministic)
    bool accP = false; int labP = 0;
    if (t == 0) {
      rem = (int)((Z >> 24) & 0xFFFFFF);
    } else {
      int ps = (int)((Z >> 24) & 0xFFFFFF), ui = (int)(Z & 0xFFFFFF);
      accP = (ps > 160) &&
             (__fdiv_rn((float)(ui - 1), fmaxf((float)ps, 1.0f)) > 0.5f);
      if (accP) {
        labP = count;
        if (b == 0 && tid == 0) ASI(&prevp[count], ps);
        count++;
      }
      rem -= ui;
    }
    if (accP && pp) {
      #pragma unroll
      for (int j = 0; j < PXT; j++)
        if ((pp >> j) & 1) iv = (iv & ~(0xFFull << (8 * j))) | ((ull)(unsigned)labP << (8 * j));
    }
    if (!((rem > 160) && (count < MAXC))) { tstop = t; break; }
    const float score = __uint_as_float((unsigned)((K >> 21) & 0x7FFFFFFF));
    if (score < 0.5f) { tstop = t; break; }
    const int sidx = 0x1FFFFF - (int)(K & 0x1FFFFF);
    rb = sidx >> 13;                                 // winner block = next reducer

    // register-only sweep (expf only within 5.5e-5 window of the threshold)
    float bsc = 0.0f; int bj = 0, psl = 0, uil = 0; unsigned ppn = 0;
    #pragma unroll
    for (int j = 0; j < PXT; j++) {
      float s = Sv.f[j];
      float d0 = __fsub_rn(Av.f[j], c0);
      float d1 = __fsub_rn(Bv.f[j], c1);
      float tt = __fadd_rn(__fmul_rn(__fmul_rn(d0, d0), s0),
                           __fmul_rn(__fmul_rn(d1, d1), s1));
      bool dok = (tt <= 0.693120f);
      if (__builtin_expect((!dok) && (tt < 0.693175f), 0))
        dok = (expf(-tt) > 0.5f);
      bool pr = dok && (fabsf(s) > 0.5f);
      if (pr) {
        ppn |= 1u << j;
        psl++;
        if (s > 0.5f) { uil++; s = -s; Sv.f[j] = s; }
      }
      float sc = (s > 0.5f) ? s : 0.0f;
      if (sc > bsc) { bsc = sc; bj = j; }
    }
    pp = ppn;
    ull bk = ((ull)__float_as_uint(bsc) << 21) | (ull)(0x1FFFFFu - (unsigned)(base + bj));
    ull bz = ((ull)(unsigned)psl << 24) | (unsigned)uil;
    ull pa = ((ull)__float_as_uint(sel8(Av, bj)) << 32) | __float_as_uint(sel8(Bv, bj));
    ull pc = ((ull)__float_as_uint(sel8(R2, bj)) << 32) | __float_as_uint(sel8(R3, bj));
    tred4(bk, bz, pa, pc);
    if (lane == 0) { lsb[wid][0] = bk; lsb[wid][1] = bz; lsb[wid][2] = pa; lsb[wid][3] = pc; }
    __syncthreads();                                 // S2
    if (wid == 0) {
      ull k = 0, z = 0, a = 0, c = 0;
      if (lane < NW) { k = lsb[lane][0]; z = lsb[lane][1]; a = lsb[lane][2]; c = lsb[lane][3]; }
      #pragma unroll
      for (int o = 8; o > 0; o >>= 1) {
        ull k2 = shfl_down_u64(k, o), z2 = shfl_down_u64(z, o),
            a2 = shfl_down_u64(a, o), c2 = shfl_down_u64(c, o);
        if (k2 > k) { k = k2; a = a2; c = c2; }
        z += z2;
      }
      if (lane == 0)
        publish(slots + (size_t)b * 8, ((ull)(unsigned)(t + 2)) << TAGSH, k, z, a, c);
    }
  }

  // ---------------- epilogue: bincount(skip 0) -> barrier -> bad -> out ---
  for (int c = tid; c < MAXC; c += BLKT) lbad[c] = 0;
  __syncthreads();
  {
    int cur = -1, acc = 0;
    #pragma unroll
    for (int j = 0; j < PXT; j++) {
      int lb = (int)((iv >> (8 * j)) & 0xFF);
      if (lb == cur) acc++;
      else { if (cur > 0) atomicAdd(&lbad[cur], acc); cur = lb; acc = 1; }
    }
    if (cur > 0) atomicAdd(&lbad[cur], acc);
  }
  __syncthreads();
  for (int c = tid + 1; c < MAXC; c += BLKT)
    if (lbad[c]) atomicAdd(&nowp[c], lbad[c]);
  __syncthreads();                                   // drains this block's atomics
  {
    const unsigned etg = (unsigned)(tstop + 2);
    if (tid == 0) ASu(slots + (size_t)b * 8, ((ull)etg) << TAGSH);
    if (b == rb) {
      if (tid < GRIDB) {
        ull* sl = slots + (size_t)tid * 8;
        while ((unsigned)(AL(sl) >> TAGSH) != etg) {}
      }
      __syncthreads();
      if (tid == 0) ASu(root, ((ull)etg) << TAGSH);
    } else {
      if (wid == 0) {
        for (;;) {
          ull w = AL(root);
          if ((unsigned)(w >> TAGSH) == etg) break;
          __builtin_amdgcn_s_sleep(1);
        }
      }
    }
    __syncthreads();
  }
  if (tid < MAXC) {
    int c = tid;
    int nw = (c == 0) ? 0 : ALI(&nowp[c]);
    int pv = ALI(&prevp[c]);
    float ratio = __fdiv_rn((float)nw, (float)(pv > 1 ? pv : 1));
    int bd = (nw != pv) && (nw > 0) && ((nw < 3 * 160) || (ratio < 0.5f));
    if (c == 0) bd = 0;
    lbad[c] = bd;
  }
  __syncthreads();
  {
    I8 O;
    #pragma unroll
    for (int j = 0; j < PXT; j++) {
      int v = (int)((iv >> (8 * j)) & 0xFF);
      O.f[j] = lbad[v] ? 0 : v;
    }
    *(int4*)(out + base) = O.v[0];
    *(int4*)(out + base + 4) = O.v[1];
  }
}

extern "C" void kernel_launch(void* const* d_in, const int* in_sizes, int n_in,
                              void* d_out, int out_size, void* d_ws, size_t ws_size,
                              hipStream_t stream) {
  const float* pred = (const float*)d_in[0];
  char* ws = (char*)d_ws;
  ull* slots = (ull*)ws;                             // 256 * 64 B
  ull* root = (ull*)(ws + 16384);                    // 64 B
  int* prevp = (int*)(ws + 16384 + 64);
  int* nowp  = (int*)(ws + 16384 + 64 + MAXC * 4);
  int* out = (int*)d_out;

  hipMemsetAsync(ws, 0, 16384 + 64, stream);         // clean tags every call
  hipLaunchKernelGGL(k_all, dim3(GRIDB), dim3(BLKT), 0, stream,
                     pred, slots, root, prevp, nowp, out);
}